// Round 3
// baseline (99.956 us; speedup 1.0000x reference)
//
#include <hip/hip_runtime.h>
#include <math.h>

#define B_DIM    1024
#define IN_DIMS  512
#define OUT_DIMS 512
#define MOD_DIM  256
#define EPS_F    1e-8f

typedef __attribute__((ext_vector_type(8))) short bf16x8;
typedef __attribute__((ext_vector_type(4))) float f32x4;

__device__ __forceinline__ unsigned short f2bf(float f) {
    union { float f; unsigned u; } c; c.f = f;
    unsigned r = c.u + 0x7fffu + ((c.u >> 16) & 1u);   // RNE
    return (unsigned short)(r >> 16);
}
__device__ __forceinline__ float bf2f(unsigned short h) {
    union { float f; unsigned u; } c; c.u = ((unsigned)h) << 16;
    return c.f;
}
__device__ __forceinline__ void split4(float4 v, ushort4& h, ushort4& l) {
    h.x = f2bf(v.x); l.x = f2bf(v.x - bf2f(h.x));
    h.y = f2bf(v.y); l.y = f2bf(v.y - bf2f(h.y));
    h.z = f2bf(v.z); l.z = f2bf(v.z - bf2f(h.z));
    h.w = f2bf(v.w); l.w = f2bf(v.w - bf2f(h.w));
}

// ---------------------------------------------------------------------------
// prep: 48 blocks, three concurrent jobs:
//   b 0..7  : w_bf = bf16(weight), colsum[i] = sum_o weight[o][i]^2 (64 cols/blk)
//   b 8..15 : mod_w -> hi/lo bf16   (64 rows/blk)
//   b 16..47: modulations -> hi/lo  (32 rows/blk)
// All conversion VALU is here, once, instead of per-GEMM-block per-K-tile.
// ---------------------------------------------------------------------------
__global__ __launch_bounds__(256) void prep(
    const float* __restrict__ weight, const float* __restrict__ mod_w,
    const float* __restrict__ mods,
    float* __restrict__ colsum, unsigned short* __restrict__ w_bf,
    unsigned short* __restrict__ mwh, unsigned short* __restrict__ mwl,
    unsigned short* __restrict__ mh,  unsigned short* __restrict__ ml)
{
    const int b = blockIdx.x, tid = threadIdx.x;
    if (b < 8) {
        __shared__ float4 sm[16][16];
        const int q = tid & 15, r = tid >> 4;
        const int col = b * 64 + q * 4;
        float4 acc = {0.f, 0.f, 0.f, 0.f};
        #pragma unroll
        for (int it = 0; it < 32; it++) {
            const int row = r + 16 * it;
            float4 v = *(const float4*)&weight[row * IN_DIMS + col];
            acc.x += v.x * v.x; acc.y += v.y * v.y;
            acc.z += v.z * v.z; acc.w += v.w * v.w;
            ushort4 h;
            h.x = f2bf(v.x); h.y = f2bf(v.y); h.z = f2bf(v.z); h.w = f2bf(v.w);
            *(ushort4*)&w_bf[row * IN_DIMS + col] = h;
        }
        sm[r][q] = acc;
        __syncthreads();
        if (tid < 16) {
            float4 s = sm[0][tid];
            #pragma unroll
            for (int j = 1; j < 16; j++) {
                float4 v = sm[j][tid];
                s.x += v.x; s.y += v.y; s.z += v.z; s.w += v.w;
            }
            *(float4*)&colsum[b * 64 + tid * 4] = s;
        }
    } else if (b < 16) {
        const int rb = b - 8;
        #pragma unroll
        for (int i = 0; i < 16; i++) {
            const int id = tid + i * 256;
            const int r = rb * 64 + (id >> 6);
            const int c = (id & 63) * 4;
            float4 v = *(const float4*)&mod_w[r * MOD_DIM + c];
            ushort4 h, l; split4(v, h, l);
            *(ushort4*)&mwh[r * MOD_DIM + c] = h;
            *(ushort4*)&mwl[r * MOD_DIM + c] = l;
        }
    } else {
        const int rb = b - 16;
        #pragma unroll
        for (int i = 0; i < 8; i++) {
            const int id = tid + i * 256;
            const int r = rb * 32 + (id >> 6);
            const int c = (id & 63) * 4;
            float4 v = *(const float4*)&mods[r * MOD_DIM + c];
            ushort4 h, l; split4(v, h, l);
            *(ushort4*)&mh[r * MOD_DIM + c] = h;
            *(ushort4*)&ml[r * MOD_DIM + c] = l;
        }
    }
}

// ---------------------------------------------------------------------------
// gemm_mod: scales = mods @ mod_w^T + mod_b via split bf16 (hi*hi+hi*lo+lo*hi),
// epilogue t = x*s*rsqrt(s^2*colsum+eps) -> t_bf.
// 64x64 tile, K=256 in TWO BK=128 iterations, 64 KB LDS, pure-copy staging,
// register prefetch of iter 1 so its load latency hides behind iter-0 MFMA.
// ---------------------------------------------------------------------------
__global__ __launch_bounds__(256) void gemm_mod(
    const unsigned short* __restrict__ Amh, const unsigned short* __restrict__ Aml,
    const unsigned short* __restrict__ Bmh, const unsigned short* __restrict__ Bml,
    const float* __restrict__ mod_b, const float* __restrict__ x,
    const float* __restrict__ colsum, unsigned short* __restrict__ t_bf)
{
    __shared__ unsigned short Ah[64 * 128], Al[64 * 128], Bh[64 * 128], Bl[64 * 128];
    const int tid = threadIdx.x;
    const int m0 = blockIdx.y * 64, n0 = blockIdx.x * 64;
    const int lane = tid & 63, wv = tid >> 6;
    const int wm = (wv >> 1) * 32, wn = (wv & 1) * 32;
    const int lr = lane & 15, lq = lane >> 4;

    // staging map: per array 4 uint4/thread; id = tid + i*256, r=id>>4, chunk=id&15
    int sr[4], sc[4];
    #pragma unroll
    for (int i = 0; i < 4; i++) { int id = tid + i * 256; sr[i] = id >> 4; sc[i] = (id & 15) * 8; }

    uint4 gah[4], gal[4], gbh[4], gbl[4];
    #pragma unroll
    for (int i = 0; i < 4; i++) {      // iter-0 loads
        gah[i] = *(const uint4*)&Amh[(m0 + sr[i]) * MOD_DIM + sc[i]];
        gal[i] = *(const uint4*)&Aml[(m0 + sr[i]) * MOD_DIM + sc[i]];
        gbh[i] = *(const uint4*)&Bmh[(n0 + sr[i]) * MOD_DIM + sc[i]];
        gbl[i] = *(const uint4*)&Bml[(n0 + sr[i]) * MOD_DIM + sc[i]];
    }
    #pragma unroll
    for (int i = 0; i < 4; i++) {
        *(uint4*)&Ah[sr[i] * 128 + sc[i]] = gah[i];
        *(uint4*)&Al[sr[i] * 128 + sc[i]] = gal[i];
        *(uint4*)&Bh[sr[i] * 128 + sc[i]] = gbh[i];
        *(uint4*)&Bl[sr[i] * 128 + sc[i]] = gbl[i];
    }
    #pragma unroll
    for (int i = 0; i < 4; i++) {      // prefetch iter-1 (latency hidden by MFMA0)
        gah[i] = *(const uint4*)&Amh[(m0 + sr[i]) * MOD_DIM + 128 + sc[i]];
        gal[i] = *(const uint4*)&Aml[(m0 + sr[i]) * MOD_DIM + 128 + sc[i]];
        gbh[i] = *(const uint4*)&Bmh[(n0 + sr[i]) * MOD_DIM + 128 + sc[i]];
        gbl[i] = *(const uint4*)&Bml[(n0 + sr[i]) * MOD_DIM + 128 + sc[i]];
    }

    f32x4 acc[2][2] = {};
    #pragma unroll
    for (int it = 0; it < 2; it++) {
        __syncthreads();
        if (it == 1) {
            #pragma unroll
            for (int i = 0; i < 4; i++) {
                *(uint4*)&Ah[sr[i] * 128 + sc[i]] = gah[i];
                *(uint4*)&Al[sr[i] * 128 + sc[i]] = gal[i];
                *(uint4*)&Bh[sr[i] * 128 + sc[i]] = gbh[i];
                *(uint4*)&Bl[sr[i] * 128 + sc[i]] = gbl[i];
            }
            __syncthreads();
        }
        #pragma unroll
        for (int kk = 0; kk < 128; kk += 32) {
            const int ko = kk + lq * 8;
            bf16x8 ah0 = *(bf16x8*)&Ah[(wm +      lr) * 128 + ko];
            bf16x8 ah1 = *(bf16x8*)&Ah[(wm + 16 + lr) * 128 + ko];
            bf16x8 al0 = *(bf16x8*)&Al[(wm +      lr) * 128 + ko];
            bf16x8 al1 = *(bf16x8*)&Al[(wm + 16 + lr) * 128 + ko];
            bf16x8 bh0 = *(bf16x8*)&Bh[(wn +      lr) * 128 + ko];
            bf16x8 bh1 = *(bf16x8*)&Bh[(wn + 16 + lr) * 128 + ko];
            bf16x8 bl0 = *(bf16x8*)&Bl[(wn +      lr) * 128 + ko];
            bf16x8 bl1 = *(bf16x8*)&Bl[(wn + 16 + lr) * 128 + ko];
            acc[0][0] = __builtin_amdgcn_mfma_f32_16x16x32_bf16(ah0, bh0, acc[0][0], 0, 0, 0);
            acc[0][1] = __builtin_amdgcn_mfma_f32_16x16x32_bf16(ah0, bh1, acc[0][1], 0, 0, 0);
            acc[1][0] = __builtin_amdgcn_mfma_f32_16x16x32_bf16(ah1, bh0, acc[1][0], 0, 0, 0);
            acc[1][1] = __builtin_amdgcn_mfma_f32_16x16x32_bf16(ah1, bh1, acc[1][1], 0, 0, 0);
            acc[0][0] = __builtin_amdgcn_mfma_f32_16x16x32_bf16(ah0, bl0, acc[0][0], 0, 0, 0);
            acc[0][1] = __builtin_amdgcn_mfma_f32_16x16x32_bf16(ah0, bl1, acc[0][1], 0, 0, 0);
            acc[1][0] = __builtin_amdgcn_mfma_f32_16x16x32_bf16(ah1, bl0, acc[1][0], 0, 0, 0);
            acc[1][1] = __builtin_amdgcn_mfma_f32_16x16x32_bf16(ah1, bl1, acc[1][1], 0, 0, 0);
            acc[0][0] = __builtin_amdgcn_mfma_f32_16x16x32_bf16(al0, bh0, acc[0][0], 0, 0, 0);
            acc[0][1] = __builtin_amdgcn_mfma_f32_16x16x32_bf16(al0, bh1, acc[0][1], 0, 0, 0);
            acc[1][0] = __builtin_amdgcn_mfma_f32_16x16x32_bf16(al1, bh0, acc[1][0], 0, 0, 0);
            acc[1][1] = __builtin_amdgcn_mfma_f32_16x16x32_bf16(al1, bh1, acc[1][1], 0, 0, 0);
        }
    }

    // C/D layout: col = lane&15, row = (lane>>4)*4 + reg
    #pragma unroll
    for (int i = 0; i < 2; i++) {
        #pragma unroll
        for (int j = 0; j < 2; j++) {
            const int gn = n0 + wn + 16 * j + lr;
            const float cs = colsum[gn];
            const float mb = mod_b[gn];
            #pragma unroll
            for (int rr = 0; rr < 4; rr++) {
                const int gm = m0 + wm + 16 * i + lq * 4 + rr;
                const float s = acc[i][j][rr] + mb;
                const float tv = x[gm * IN_DIMS + gn] * s * rsqrtf(s * s * cs + EPS_F);
                t_bf[gm * IN_DIMS + gn] = f2bf(tv);
            }
        }
    }
}

// ---------------------------------------------------------------------------
// gemm_out: out = t_bf @ w_bf^T + bias. 64x64 tile, K=512 in TWO BK=256
// iterations, 64 KB LDS, register prefetch of iter 1.
// ---------------------------------------------------------------------------
__global__ __launch_bounds__(256) void gemm_out(
    const unsigned short* __restrict__ A,  // t_bf [1024,512]
    const unsigned short* __restrict__ Bw, // w_bf [512,512]
    const float* __restrict__ bias, float* __restrict__ out)
{
    __shared__ unsigned short As[64 * 256], Bs[64 * 256];
    const int tid = threadIdx.x;
    const int m0 = blockIdx.y * 64, n0 = blockIdx.x * 64;
    const int lane = tid & 63, wv = tid >> 6;
    const int wm = (wv >> 1) * 32, wn = (wv & 1) * 32;
    const int lr = lane & 15, lq = lane >> 4;

    // staging map: per array 8 uint4/thread; id = tid + i*256, r=id>>5, chunk=id&31
    int sr[8], sc[8];
    #pragma unroll
    for (int i = 0; i < 8; i++) { int id = tid + i * 256; sr[i] = id >> 5; sc[i] = (id & 31) * 8; }

    uint4 ga[8], gb[8];
    #pragma unroll
    for (int i = 0; i < 8; i++) {
        ga[i] = *(const uint4*)&A [(m0 + sr[i]) * IN_DIMS + sc[i]];
        gb[i] = *(const uint4*)&Bw[(n0 + sr[i]) * IN_DIMS + sc[i]];
    }
    #pragma unroll
    for (int i = 0; i < 8; i++) {
        *(uint4*)&As[sr[i] * 256 + sc[i]] = ga[i];
        *(uint4*)&Bs[sr[i] * 256 + sc[i]] = gb[i];
    }
    #pragma unroll
    for (int i = 0; i < 8; i++) {      // prefetch iter-1
        ga[i] = *(const uint4*)&A [(m0 + sr[i]) * IN_DIMS + 256 + sc[i]];
        gb[i] = *(const uint4*)&Bw[(n0 + sr[i]) * IN_DIMS + 256 + sc[i]];
    }

    f32x4 acc[2][2] = {};
    #pragma unroll
    for (int it = 0; it < 2; it++) {
        __syncthreads();
        if (it == 1) {
            #pragma unroll
            for (int i = 0; i < 8; i++) {
                *(uint4*)&As[sr[i] * 256 + sc[i]] = ga[i];
                *(uint4*)&Bs[sr[i] * 256 + sc[i]] = gb[i];
            }
            __syncthreads();
        }
        #pragma unroll
        for (int kk = 0; kk < 256; kk += 32) {
            const int ko = kk + lq * 8;
            bf16x8 a0 = *(bf16x8*)&As[(wm +      lr) * 256 + ko];
            bf16x8 a1 = *(bf16x8*)&As[(wm + 16 + lr) * 256 + ko];
            bf16x8 b0 = *(bf16x8*)&Bs[(wn +      lr) * 256 + ko];
            bf16x8 b1 = *(bf16x8*)&Bs[(wn + 16 + lr) * 256 + ko];
            acc[0][0] = __builtin_amdgcn_mfma_f32_16x16x32_bf16(a0, b0, acc[0][0], 0, 0, 0);
            acc[0][1] = __builtin_amdgcn_mfma_f32_16x16x32_bf16(a0, b1, acc[0][1], 0, 0, 0);
            acc[1][0] = __builtin_amdgcn_mfma_f32_16x16x32_bf16(a1, b0, acc[1][0], 0, 0, 0);
            acc[1][1] = __builtin_amdgcn_mfma_f32_16x16x32_bf16(a1, b1, acc[1][1], 0, 0, 0);
        }
    }

    #pragma unroll
    for (int i = 0; i < 2; i++) {
        #pragma unroll
        for (int j = 0; j < 2; j++) {
            const int gn = n0 + wn + 16 * j + lr;
            const float bv = bias[gn];
            #pragma unroll
            for (int rr = 0; rr < 4; rr++) {
                const int gm = m0 + wm + 16 * i + lq * 4 + rr;
                out[gm * OUT_DIMS + gn] = acc[i][j][rr] + bv;
            }
        }
    }
}

extern "C" void kernel_launch(void* const* d_in, const int* in_sizes, int n_in,
                              void* d_out, int out_size, void* d_ws, size_t ws_size,
                              hipStream_t stream)
{
    const float* modulations = (const float*)d_in[0]; // [1024, 256]
    const float* x           = (const float*)d_in[1]; // [1024, 512]
    const float* weight      = (const float*)d_in[2]; // [512, 512]
    const float* bias        = (const float*)d_in[3]; // [512]
    const float* mod_w       = (const float*)d_in[4]; // [512, 256]
    const float* mod_b       = (const float*)d_in[5]; // [512]
    float* out = (float*)d_out;                       // [1024, 512]

    char* wsb = (char*)d_ws;
    float* colsum        = (float*)wsb;                          // 2 KB (pad 4K)
    unsigned short* w_bf = (unsigned short*)(wsb + 4096);        // 512 KB
    unsigned short* t_bf = (unsigned short*)(wsb + 4096 + 524288);          // 1 MB
    unsigned short* mwh  = (unsigned short*)(wsb + 4096 + 524288 + 1048576);           // 256 KB
    unsigned short* mwl  = (unsigned short*)(wsb + 4096 + 524288 + 1048576 + 262144);  // 256 KB
    unsigned short* mh   = (unsigned short*)(wsb + 4096 + 524288 + 1048576 + 524288);  // 512 KB
    unsigned short* ml   = (unsigned short*)(wsb + 4096 + 524288 + 1048576 + 524288 + 524288);

    prep<<<48, 256, 0, stream>>>(weight, mod_w, modulations,
                                 colsum, w_bf, mwh, mwl, mh, ml);

    gemm_mod<<<dim3(IN_DIMS / 64, B_DIM / 64), 256, 0, stream>>>(
        mh, ml, mwh, mwl, mod_b, x, colsum, t_bf);

    gemm_out<<<dim3(OUT_DIMS / 64, B_DIM / 64), 256, 0, stream>>>(
        t_bf, w_bf, bias, out);
}

// Round 4
// 77.441 us; speedup vs baseline: 1.2907x; 1.2907x over previous
//
#include <hip/hip_runtime.h>
#include <math.h>

#define B_DIM    1024
#define IN_DIMS  512
#define OUT_DIMS 512
#define MOD_DIM  256
#define EPS_F    1e-8f

typedef __attribute__((ext_vector_type(8))) short bf16x8;
typedef __attribute__((ext_vector_type(4))) float f32x4;

__device__ __forceinline__ unsigned short f2bf(float f) {
    union { float f; unsigned u; } c; c.f = f;
    unsigned r = c.u + 0x7fffu + ((c.u >> 16) & 1u);   // RNE
    return (unsigned short)(r >> 16);
}
__device__ __forceinline__ float bf2f(unsigned short h) {
    union { float f; unsigned u; } c; c.u = ((unsigned)h) << 16;
    return c.f;
}

// ---------------------------------------------------------------------------
// K1: fused colsum + split-bf16 conversion + mod-GEMM + demod epilogue -> t_bf
// grid (8 n-tiles, 32 m-tiles) = 256 blocks (1/CU), 256 thr = 4 waves.
// Tile: 32 (m=batch) x 64 (n=in_dim), K=256 one-shot in LDS, ONE main barrier.
// Each block computes its own colsum[n0..n0+63] (128KB weight read, L2-shared)
// and converts its own A/B tiles (hi/lo split) -- no prep kernel, no global
// dependency. LDS rows padded to 264 elems (528B = 33x16B, bank shift 4/row
// -> 2-way aliasing = free).
// s = hi*hi + hi*lo + lo*hi (fp32-grade; epilogue is sign(s)-sensitive).
// ---------------------------------------------------------------------------
#define LP1 264
__global__ __launch_bounds__(256) void k1_mod(
    const float* __restrict__ mods,    // [1024,256]
    const float* __restrict__ mod_w,   // [512,256]
    const float* __restrict__ mod_b,   // [512]
    const float* __restrict__ weight,  // [512,512]
    const float* __restrict__ x,       // [1024,512]
    unsigned short* __restrict__ t_bf) // [1024,512]
{
    __shared__ unsigned short Ah[32 * LP1], Al[32 * LP1];
    __shared__ unsigned short Bh[64 * LP1], Bl[64 * LP1];
    __shared__ float4 csm[16][16];
    __shared__ float colsum_s[64];

    const int tid = threadIdx.x;
    const int n0 = blockIdx.x * 64;
    const int m0 = blockIdx.y * 32;
    const int lane = tid & 63, wv = tid >> 6;
    const int wm = (wv >> 1) * 16, wn = (wv & 1) * 32;
    const int lr = lane & 15, lq = lane >> 4;

    // ---- stage A (mods, 32x256): 8 float4/thread, split hi/lo ----
    #pragma unroll
    for (int i = 0; i < 8; i++) {
        const int id = tid + i * 256;
        const int r = id >> 6, c4 = id & 63;
        float4 v = *(const float4*)&mods[(m0 + r) * MOD_DIM + c4 * 4];
        ushort4 h, l;
        h.x = f2bf(v.x); l.x = f2bf(v.x - bf2f(h.x));
        h.y = f2bf(v.y); l.y = f2bf(v.y - bf2f(h.y));
        h.z = f2bf(v.z); l.z = f2bf(v.z - bf2f(h.z));
        h.w = f2bf(v.w); l.w = f2bf(v.w - bf2f(h.w));
        *(ushort4*)&Ah[r * LP1 + c4 * 4] = h;
        *(ushort4*)&Al[r * LP1 + c4 * 4] = l;
    }
    // ---- stage B (mod_w, 64x256): 16 float4/thread, split hi/lo ----
    #pragma unroll
    for (int i = 0; i < 16; i++) {
        const int id = tid + i * 256;
        const int r = id >> 6, c4 = id & 63;
        float4 v = *(const float4*)&mod_w[(n0 + r) * MOD_DIM + c4 * 4];
        ushort4 h, l;
        h.x = f2bf(v.x); l.x = f2bf(v.x - bf2f(h.x));
        h.y = f2bf(v.y); l.y = f2bf(v.y - bf2f(h.y));
        h.z = f2bf(v.z); l.z = f2bf(v.z - bf2f(h.z));
        h.w = f2bf(v.w); l.w = f2bf(v.w - bf2f(h.w));
        *(ushort4*)&Bh[r * LP1 + c4 * 4] = h;
        *(ushort4*)&Bl[r * LP1 + c4 * 4] = l;
    }

    // ---- colsum for this block's 64 cols: 32 coalesced float4 rounds ----
    {
        const int c4 = tid & 15, rr = tid >> 4;
        float4 acc = {0.f, 0.f, 0.f, 0.f};
        #pragma unroll
        for (int it = 0; it < 32; it++) {
            const int row = rr + 16 * it;
            float4 v = *(const float4*)&weight[row * IN_DIMS + n0 + c4 * 4];
            acc.x += v.x * v.x; acc.y += v.y * v.y;
            acc.z += v.z * v.z; acc.w += v.w * v.w;
        }
        csm[rr][c4] = acc;
    }
    __syncthreads();
    if (tid < 16) {
        float4 s = csm[0][tid];
        #pragma unroll
        for (int j = 1; j < 16; j++) {
            float4 v = csm[j][tid];
            s.x += v.x; s.y += v.y; s.z += v.z; s.w += v.w;
        }
        *(float4*)&colsum_s[tid * 4] = s;
    }

    // ---- MFMA: 8 kk-steps, 6 MFMA each (hh, hl, lh) ----
    f32x4 acc[2] = {};
    #pragma unroll
    for (int kk = 0; kk < 256; kk += 32) {
        const int ko = kk + lq * 8;
        bf16x8 ah = *(bf16x8*)&Ah[(wm + lr) * LP1 + ko];
        bf16x8 al = *(bf16x8*)&Al[(wm + lr) * LP1 + ko];
        bf16x8 bh0 = *(bf16x8*)&Bh[(wn +      lr) * LP1 + ko];
        bf16x8 bh1 = *(bf16x8*)&Bh[(wn + 16 + lr) * LP1 + ko];
        bf16x8 bl0 = *(bf16x8*)&Bl[(wn +      lr) * LP1 + ko];
        bf16x8 bl1 = *(bf16x8*)&Bl[(wn + 16 + lr) * LP1 + ko];
        acc[0] = __builtin_amdgcn_mfma_f32_16x16x32_bf16(ah, bh0, acc[0], 0, 0, 0);
        acc[1] = __builtin_amdgcn_mfma_f32_16x16x32_bf16(ah, bh1, acc[1], 0, 0, 0);
        acc[0] = __builtin_amdgcn_mfma_f32_16x16x32_bf16(ah, bl0, acc[0], 0, 0, 0);
        acc[1] = __builtin_amdgcn_mfma_f32_16x16x32_bf16(ah, bl1, acc[1], 0, 0, 0);
        acc[0] = __builtin_amdgcn_mfma_f32_16x16x32_bf16(al, bh0, acc[0], 0, 0, 0);
        acc[1] = __builtin_amdgcn_mfma_f32_16x16x32_bf16(al, bh1, acc[1], 0, 0, 0);
    }
    __syncthreads();   // colsum_s visibility for all waves

    // ---- epilogue: s -> t = x*s*rsqrt(s^2*colsum+eps) -> bf16 ----
    // C/D layout: col = lane&15, row = (lane>>4)*4 + reg
    #pragma unroll
    for (int j = 0; j < 2; j++) {
        const int ln = wn + 16 * j + lr;
        const int gn = n0 + ln;
        const float cs = colsum_s[ln];
        const float mb = mod_b[gn];
        #pragma unroll
        for (int rr = 0; rr < 4; rr++) {
            const int gm = m0 + wm + lq * 4 + rr;
            const float s = acc[j][rr] + mb;
            const float tv = x[gm * IN_DIMS + gn] * s * rsqrtf(s * s * cs + EPS_F);
            t_bf[gm * IN_DIMS + gn] = f2bf(tv);
        }
    }
}

// ---------------------------------------------------------------------------
// K2: out = t_bf @ bf16(weight)^T + bias, weight converted inline (no prep).
// grid (8 n-tiles, 32 m-tiles) = 256 blocks (1/CU), 256 thr = 4 waves.
// Tile 32 (m) x 64 (n), K=512 one-shot in LDS, ONE barrier.
// LDS rows padded to 536 elems (1072B = 67x16B, bank shift 12/row -> 2-way).
// ---------------------------------------------------------------------------
#define LP2 536
__global__ __launch_bounds__(256) void k2_out(
    const unsigned short* __restrict__ t_bf, // [1024,512]
    const float* __restrict__ weight,        // [512,512]
    const float* __restrict__ bias,          // [512]
    float* __restrict__ out)                 // [1024,512]
{
    __shared__ unsigned short As[32 * LP2];
    __shared__ unsigned short Bs[64 * LP2];

    const int tid = threadIdx.x;
    const int n0 = blockIdx.x * 64;
    const int m0 = blockIdx.y * 32;
    const int lane = tid & 63, wv = tid >> 6;
    const int wm = (wv >> 1) * 16, wn = (wv & 1) * 32;
    const int lr = lane & 15, lq = lane >> 4;

    // ---- stage A (t_bf, 32x512 bf16): 8 uint4 copies/thread ----
    #pragma unroll
    for (int i = 0; i < 8; i++) {
        const int id = tid + i * 256;
        const int r = id >> 6, c8 = id & 63;
        *(uint4*)&As[r * LP2 + c8 * 8] =
            *(const uint4*)&t_bf[(m0 + r) * IN_DIMS + c8 * 8];
    }
    // ---- stage B (weight fp32 -> bf16, 64x512): 32 float4/thread ----
    #pragma unroll
    for (int i = 0; i < 32; i++) {
        const int id = tid + i * 256;
        const int r = id >> 7, c4 = id & 127;
        float4 v = *(const float4*)&weight[(n0 + r) * IN_DIMS + c4 * 4];
        ushort4 h;
        h.x = f2bf(v.x); h.y = f2bf(v.y); h.z = f2bf(v.z); h.w = f2bf(v.w);
        *(ushort4*)&Bs[r * LP2 + c4 * 4] = h;
    }
    __syncthreads();

    f32x4 acc[2] = {};
    #pragma unroll
    for (int kk = 0; kk < 512; kk += 32) {
        const int ko = kk + lq * 8;
        bf16x8 a  = *(bf16x8*)&As[(wm + lr) * LP2 + ko];
        bf16x8 b0 = *(bf16x8*)&Bs[(wn +      lr) * LP2 + ko];
        bf16x8 b1 = *(bf16x8*)&Bs[(wn + 16 + lr) * LP2 + ko];
        acc[0] = __builtin_amdgcn_mfma_f32_16x16x32_bf16(a, b0, acc[0], 0, 0, 0);
        acc[1] = __builtin_amdgcn_mfma_f32_16x16x32_bf16(a, b1, acc[1], 0, 0, 0);
    }

    #pragma unroll
    for (int j = 0; j < 2; j++) {
        const int gn = n0 + wn + 16 * j + lr;
        const float bv = bias[gn];
        #pragma unroll
        for (int rr = 0; rr < 4; rr++) {
            const int gm = m0 + wm + lq * 4 + rr;
            out[gm * OUT_DIMS + gn] = acc[j][rr] + bv;
        }
    }
}

extern "C" void kernel_launch(void* const* d_in, const int* in_sizes, int n_in,
                              void* d_out, int out_size, void* d_ws, size_t ws_size,
                              hipStream_t stream)
{
    const float* modulations = (const float*)d_in[0]; // [1024, 256]
    const float* x           = (const float*)d_in[1]; // [1024, 512]
    const float* weight      = (const float*)d_in[2]; // [512, 512]
    const float* bias        = (const float*)d_in[3]; // [512]
    const float* mod_w       = (const float*)d_in[4]; // [512, 256]
    const float* mod_b       = (const float*)d_in[5]; // [512]
    float* out = (float*)d_out;                       // [1024, 512]

    unsigned short* t_bf = (unsigned short*)d_ws;     // 1 MB

    k1_mod<<<dim3(8, 32), 256, 0, stream>>>(
        modulations, mod_w, mod_b, weight, x, t_bf);

    k2_out<<<dim3(8, 32), 256, 0, stream>>>(
        t_bf, weight, bias, out);
}